// Round 1
// baseline (211.041 us; speedup 1.0000x reference)
//
#include <hip/hip_runtime.h>
#include <math.h>

// BinaryTreeRNN: h = x@W_leaf.T + b_leaf (N,8), then 3 tree-combine levels
// (8->4->2->1), out = h[:,0]. Memory-bound: 64B read + 4B write per row.

__global__ __launch_bounds__(256) void tree_rnn_kernel(
    const float* __restrict__ x,
    const float* __restrict__ W_leaf,
    const float* __restrict__ b_leaf,
    const float* __restrict__ w0,
    const float* __restrict__ w1,
    const float* __restrict__ w2,
    const float* __restrict__ b0,
    const float* __restrict__ b1,
    const float* __restrict__ b2,
    const float* __restrict__ om0,
    const float* __restrict__ om1,
    const float* __restrict__ om2,
    float* __restrict__ out,
    int n)
{
    // ---- hoist weights into registers (wave-uniform loads, loop-invariant) ----
    float W[8][16];
#pragma unroll
    for (int j = 0; j < 8; ++j)
#pragma unroll
        for (int v = 0; v < 16; ++v)
            W[j][v] = W_leaf[j * 16 + v];

    float bl[8];
#pragma unroll
    for (int j = 0; j < 8; ++j) bl[j] = b_leaf[j];

    // ---- fold softmax(om) and w,b into per-node affine coefficients ----
    // node value: w*(sm0*s + sm1*(l*r) + sm2*sin(s) + sm3*s) + b
    //           = A*s + B*(l*r) + C*sin(s) + D
    float A2[4], B2[4], C2[4], D2[4];
#pragma unroll
    for (int j = 0; j < 4; ++j) {
        float o0 = om2[j * 4 + 0], o1 = om2[j * 4 + 1];
        float o2 = om2[j * 4 + 2], o3 = om2[j * 4 + 3];
        float m  = fmaxf(fmaxf(o0, o1), fmaxf(o2, o3));
        float e0 = expf(o0 - m), e1 = expf(o1 - m);
        float e2 = expf(o2 - m), e3 = expf(o3 - m);
        float inv = 1.0f / (e0 + e1 + e2 + e3);
        float wj = w2[j];
        A2[j] = wj * (e0 + e3) * inv;
        B2[j] = wj * e1 * inv;
        C2[j] = wj * e2 * inv;
        D2[j] = b2[j];
    }
    float A1[2], B1[2], C1[2], D1[2];
#pragma unroll
    for (int j = 0; j < 2; ++j) {
        float o0 = om1[j * 4 + 0], o1 = om1[j * 4 + 1];
        float o2 = om1[j * 4 + 2], o3 = om1[j * 4 + 3];
        float m  = fmaxf(fmaxf(o0, o1), fmaxf(o2, o3));
        float e0 = expf(o0 - m), e1 = expf(o1 - m);
        float e2 = expf(o2 - m), e3 = expf(o3 - m);
        float inv = 1.0f / (e0 + e1 + e2 + e3);
        float wj = w1[j];
        A1[j] = wj * (e0 + e3) * inv;
        B1[j] = wj * e1 * inv;
        C1[j] = wj * e2 * inv;
        D1[j] = b1[j];
    }
    float A0, B0, C0, D0;
    {
        float o0 = om0[0], o1 = om0[1], o2 = om0[2], o3 = om0[3];
        float m  = fmaxf(fmaxf(o0, o1), fmaxf(o2, o3));
        float e0 = expf(o0 - m), e1 = expf(o1 - m);
        float e2 = expf(o2 - m), e3 = expf(o3 - m);
        float inv = 1.0f / (e0 + e1 + e2 + e3);
        float wj = w0[0];
        A0 = wj * (e0 + e3) * inv;
        B0 = wj * e1 * inv;
        C0 = wj * e2 * inv;
        D0 = b0[0];
    }

    // ---- grid-stride row loop ----
    const long long stride = (long long)gridDim.x * blockDim.x;
    for (long long i = (long long)blockIdx.x * blockDim.x + threadIdx.x;
         i < n; i += stride) {
        const float4* xr = reinterpret_cast<const float4*>(x) + i * 4;
        float4 va = xr[0];
        float4 vb = xr[1];
        float4 vc = xr[2];
        float4 vd = xr[3];
        float xv[16] = {va.x, va.y, va.z, va.w,
                        vb.x, vb.y, vb.z, vb.w,
                        vc.x, vc.y, vc.z, vc.w,
                        vd.x, vd.y, vd.z, vd.w};

        // leaf matvec: h[j] = b_leaf[j] + sum_v x[v]*W[j][v]
        float h[8];
#pragma unroll
        for (int j = 0; j < 8; ++j) {
            float acc = bl[j];
#pragma unroll
            for (int v = 0; v < 16; ++v)
                acc = fmaf(xv[v], W[j][v], acc);
            h[j] = acc;
        }

        // level 2: 8 -> 4
        float g4[4];
#pragma unroll
        for (int j = 0; j < 4; ++j) {
            float l = h[2 * j], r = h[2 * j + 1];
            float s = l + r;
            g4[j] = fmaf(A2[j], s,
                     fmaf(B2[j], l * r,
                      fmaf(C2[j], sinf(s), D2[j])));
        }

        // level 1: 4 -> 2
        float g2[2];
#pragma unroll
        for (int j = 0; j < 2; ++j) {
            float l = g4[2 * j], r = g4[2 * j + 1];
            float s = l + r;
            g2[j] = fmaf(A1[j], s,
                     fmaf(B1[j], l * r,
                      fmaf(C1[j], sinf(s), D1[j])));
        }

        // level 0: 2 -> 1
        {
            float l = g2[0], r = g2[1];
            float s = l + r;
            float o = fmaf(A0, s,
                       fmaf(B0, l * r,
                        fmaf(C0, sinf(s), D0)));
            out[i] = o;
        }
    }
}

extern "C" void kernel_launch(void* const* d_in, const int* in_sizes, int n_in,
                              void* d_out, int out_size, void* d_ws, size_t ws_size,
                              hipStream_t stream) {
    const float* x      = (const float*)d_in[0];
    const float* W_leaf = (const float*)d_in[1];
    const float* b_leaf = (const float*)d_in[2];
    const float* w0     = (const float*)d_in[3];
    const float* w1     = (const float*)d_in[4];
    const float* w2     = (const float*)d_in[5];
    const float* b0     = (const float*)d_in[6];
    const float* b1     = (const float*)d_in[7];
    const float* b2     = (const float*)d_in[8];
    const float* om0    = (const float*)d_in[9];
    const float* om1    = (const float*)d_in[10];
    const float* om2    = (const float*)d_in[11];
    float* out = (float*)d_out;

    int n = in_sizes[0] / 16;   // rows
    int block = 256;
    int grid = 2048;            // grid-stride: ~3.8 rows/thread, amortizes softmax hoist
    if (grid > (n + block - 1) / block) grid = (n + block - 1) / block;

    tree_rnn_kernel<<<grid, block, 0, stream>>>(
        x, W_leaf, b_leaf, w0, w1, w2, b0, b1, b2, om0, om1, om2, out, n);
}

// Round 2
// 206.424 us; speedup vs baseline: 1.0224x; 1.0224x over previous
//
#include <hip/hip_runtime.h>
#include <math.h>

// BinaryTreeRNN: h = x@W_leaf.T + b_leaf (N,8), then 3 tree-combine levels
// (8->4->2->1), out = h[:,0]. Memory-bound: 64B read + 4B write per row,
// floor ~21.6 us at 6.3 TB/s.
//
// R1 lesson: grid-stride loop + hoisted W[8][16] register array => ~200 VGPR
// live range => scratch spill reloaded EVERY iteration (~1 GB scratch traffic,
// 211 us). Fix: one row per thread (no loop => short W live ranges), and all
// softmax/coefficient folding moved to a 1-thread prep kernel -> d_ws, loaded
// as wave-uniform scalars by the main kernel.

// ws layout (floats):
// [0:4)  A2   [4:8)  B2   [8:12) C2   [12:16) D2
// [16:18) A1  [18:20) B1  [20:22) C1  [22:24) D1
// [24] A0 [25] B0 [26] C0 [27] D0
// [28:36) b_leaf
__global__ void prep_kernel(
    const float* __restrict__ b_leaf,
    const float* __restrict__ w0, const float* __restrict__ w1,
    const float* __restrict__ w2,
    const float* __restrict__ b0, const float* __restrict__ b1,
    const float* __restrict__ b2,
    const float* __restrict__ om0, const float* __restrict__ om1,
    const float* __restrict__ om2,
    float* __restrict__ ws)
{
    // single thread: fold softmax(om) and w,b into per-node affine coeffs
    // node value = A*s + B*(l*r) + C*sin(s) + D
    for (int j = 0; j < 4; ++j) {
        float o0 = om2[j*4+0], o1 = om2[j*4+1], o2 = om2[j*4+2], o3 = om2[j*4+3];
        float m  = fmaxf(fmaxf(o0, o1), fmaxf(o2, o3));
        float e0 = expf(o0-m), e1 = expf(o1-m), e2 = expf(o2-m), e3 = expf(o3-m);
        float inv = 1.0f / (e0+e1+e2+e3);
        float wj = w2[j];
        ws[0+j]  = wj * (e0+e3) * inv;
        ws[4+j]  = wj * e1 * inv;
        ws[8+j]  = wj * e2 * inv;
        ws[12+j] = b2[j];
    }
    for (int j = 0; j < 2; ++j) {
        float o0 = om1[j*4+0], o1 = om1[j*4+1], o2 = om1[j*4+2], o3 = om1[j*4+3];
        float m  = fmaxf(fmaxf(o0, o1), fmaxf(o2, o3));
        float e0 = expf(o0-m), e1 = expf(o1-m), e2 = expf(o2-m), e3 = expf(o3-m);
        float inv = 1.0f / (e0+e1+e2+e3);
        float wj = w1[j];
        ws[16+j] = wj * (e0+e3) * inv;
        ws[18+j] = wj * e1 * inv;
        ws[20+j] = wj * e2 * inv;
        ws[22+j] = b1[j];
    }
    {
        float o0 = om0[0], o1 = om0[1], o2 = om0[2], o3 = om0[3];
        float m  = fmaxf(fmaxf(o0, o1), fmaxf(o2, o3));
        float e0 = expf(o0-m), e1 = expf(o1-m), e2 = expf(o2-m), e3 = expf(o3-m);
        float inv = 1.0f / (e0+e1+e2+e3);
        float wj = w0[0];
        ws[24] = wj * (e0+e3) * inv;
        ws[25] = wj * e1 * inv;
        ws[26] = wj * e2 * inv;
        ws[27] = b0[0];
    }
    for (int j = 0; j < 8; ++j) ws[28+j] = b_leaf[j];
}

__global__ __launch_bounds__(256) void tree_rnn_kernel(
    const float* __restrict__ x,
    const float* __restrict__ W_leaf,
    const float* __restrict__ coef,
    float* __restrict__ out,
    int n)
{
    int i = blockIdx.x * 256 + threadIdx.x;
    if (i >= n) return;

    // ---- load row (coalesced: 4x dwordx4 per lane) ----
    const float4* xr = reinterpret_cast<const float4*>(x) + (long long)i * 4;
    float4 va = xr[0];
    float4 vb = xr[1];
    float4 vc = xr[2];
    float4 vd = xr[3];
    float xv[16] = {va.x, va.y, va.z, va.w,
                    vb.x, vb.y, vb.z, vb.w,
                    vc.x, vc.y, vc.z, vc.w,
                    vd.x, vd.y, vd.z, vd.w};

    // ---- leaf matvec: W_leaf rows read inline (wave-uniform -> s_load,
    //      consumed row-by-row so live range stays ~16 regs) ----
    float h[8];
#pragma unroll
    for (int j = 0; j < 8; ++j) {
        float acc = coef[28 + j];           // b_leaf[j]
#pragma unroll
        for (int v = 0; v < 16; ++v)
            acc = fmaf(xv[v], W_leaf[j * 16 + v], acc);
        h[j] = acc;
    }

    // ---- level 2: 8 -> 4 ----
    float g4[4];
#pragma unroll
    for (int j = 0; j < 4; ++j) {
        float l = h[2*j], r = h[2*j+1];
        float s = l + r;
        g4[j] = fmaf(coef[0+j], s,
                 fmaf(coef[4+j], l * r,
                  fmaf(coef[8+j], sinf(s), coef[12+j])));
    }

    // ---- level 1: 4 -> 2 ----
    float g2[2];
#pragma unroll
    for (int j = 0; j < 2; ++j) {
        float l = g4[2*j], r = g4[2*j+1];
        float s = l + r;
        g2[j] = fmaf(coef[16+j], s,
                 fmaf(coef[18+j], l * r,
                  fmaf(coef[20+j], sinf(s), coef[22+j])));
    }

    // ---- level 0: 2 -> 1 ----
    {
        float l = g2[0], r = g2[1];
        float s = l + r;
        out[i] = fmaf(coef[24], s,
                  fmaf(coef[25], l * r,
                   fmaf(coef[26], sinf(s), coef[27])));
    }
}

extern "C" void kernel_launch(void* const* d_in, const int* in_sizes, int n_in,
                              void* d_out, int out_size, void* d_ws, size_t ws_size,
                              hipStream_t stream) {
    const float* x      = (const float*)d_in[0];
    const float* W_leaf = (const float*)d_in[1];
    const float* b_leaf = (const float*)d_in[2];
    const float* w0     = (const float*)d_in[3];
    const float* w1     = (const float*)d_in[4];
    const float* w2     = (const float*)d_in[5];
    const float* b0     = (const float*)d_in[6];
    const float* b1     = (const float*)d_in[7];
    const float* b2     = (const float*)d_in[8];
    const float* om0    = (const float*)d_in[9];
    const float* om1    = (const float*)d_in[10];
    const float* om2    = (const float*)d_in[11];
    float* out  = (float*)d_out;
    float* coef = (float*)d_ws;   // 36 floats

    int n = in_sizes[0] / 16;     // rows

    prep_kernel<<<1, 1, 0, stream>>>(b_leaf, w0, w1, w2, b0, b1, b2,
                                     om0, om1, om2, coef);

    int block = 256;
    int grid = (n + block - 1) / block;
    tree_rnn_kernel<<<grid, block, 0, stream>>>(x, W_leaf, coef, out, n);
}